// Round 1
// baseline (1126.038 us; speedup 1.0000x reference)
//
#include <hip/hip_runtime.h>

// SubregionFeatureExtractor: per-batch, per-time, per-region channel means.
// features [B,T,C,D,H,W] f32, segmentation [B,1,D,H,W] int32 in 0..32.
// out [B,T,32,C] f32: mean over voxels with seg==r (r=1..32); empty -> 0.

#define BB 2
#define TT 8
#define CC 64
#define NVOX 110592      // 48*48*48
#define NREG 32
#define RS 33            // region slots incl. background 0
#define PAD 65           // LDS region stride (65%32==1 -> bank=(r+c)%32)
#define WCOPY (RS*PAD)   // floats per wave copy = 2145
#define CHUNK 2048       // voxels per block in seg_sum

// ---------------- kernel 1: per-batch region histogram -------------------
__global__ __launch_bounds__(256) void seg_hist(const int* __restrict__ seg,
                                                float* __restrict__ counts) {
    __shared__ float h[4 * RS];
    const int tid = threadIdx.x;
    const int w = tid >> 6;
    for (int i = tid; i < 4 * RS; i += 256) h[i] = 0.f;
    __syncthreads();

    const int base = blockIdx.x * 1024 + tid * 4;  // flattened over B*NVOX
    const int b = base / NVOX;                      // block fully inside one batch
    const int4 s4 = *(const int4*)(seg + base);
    atomicAdd(&h[w * RS + s4.x], 1.f);
    atomicAdd(&h[w * RS + s4.y], 1.f);
    atomicAdd(&h[w * RS + s4.z], 1.f);
    atomicAdd(&h[w * RS + s4.w], 1.f);
    __syncthreads();

    if (tid < RS) {
        const float v = h[tid] + h[RS + tid] + h[2 * RS + tid] + h[3 * RS + tid];
        atomicAdd(&counts[b * RS + tid], v);
    }
}

// ---------------- kernel 2: streaming region sums ------------------------
// grid: (NVOX/CHUNK, T, B), block 256 (4 waves). Per-wave LDS accumulator
// copies cut intra-instruction same-address collisions; pad 65 spreads banks.
__global__ __launch_bounds__(256) void seg_sum(const float* __restrict__ feat,
                                               const int* __restrict__ seg,
                                               float* __restrict__ out) {
    __shared__ float s[4 * WCOPY];  // 34320 B
    const int tid = threadIdx.x;
    const int w = tid >> 6;
    const int b = blockIdx.z;
    const int t = blockIdx.y;

    for (int i = tid; i < 4 * WCOPY; i += 256) s[i] = 0.f;
    __syncthreads();

    const int nbase = blockIdx.x * CHUNK;
    const float* __restrict__ fbt = feat + (size_t)(b * TT + t) * CC * NVOX;
    const int* __restrict__ segb = seg + (size_t)b * NVOX;

    for (int tile = 0; tile < CHUNK / 1024; ++tile) {
        const int n0 = nbase + tile * 1024 + tid * 4;
        const int4 s4 = *(const int4*)(segb + n0);
        const int o0 = w * WCOPY + s4.x * PAD;
        const int o1 = w * WCOPY + s4.y * PAD;
        const int o2 = w * WCOPY + s4.z * PAD;
        const int o3 = w * WCOPY + s4.w * PAD;
        const float* __restrict__ fp = fbt + n0;
        #pragma unroll 8
        for (int c = 0; c < CC; ++c) {
            const float4 f = *(const float4*)(fp + (size_t)c * NVOX);
            atomicAdd(&s[o0 + c], f.x);
            atomicAdd(&s[o1 + c], f.y);
            atomicAdd(&s[o2 + c], f.z);
            atomicAdd(&s[o3 + c], f.w);
        }
    }
    __syncthreads();

    // reduce the 4 wave copies (skip background region 0) -> global atomics
    float* __restrict__ outbt = out + (size_t)(b * TT + t) * NREG * CC;
    for (int i = tid; i < NREG * CC; i += 256) {
        const int r = (i >> 6) + 1;  // 1..32
        const int c = i & 63;
        const int off = r * PAD + c;
        const float v = s[off] + s[WCOPY + off] + s[2 * WCOPY + off] + s[3 * WCOPY + off];
        atomicAdd(&outbt[i], v);
    }
}

// ---------------- kernel 3: divide by counts -----------------------------
__global__ __launch_bounds__(256) void seg_div(float* __restrict__ out,
                                               const float* __restrict__ counts) {
    const int i = blockIdx.x * 256 + threadIdx.x;       // out_size = 32768
    const int b = i >> 14;                              // / (TT*NREG*CC)
    const int r = ((i >> 6) & 31) + 1;                  // region 1..32
    const float cnt = counts[b * RS + r];
    const float v = out[i];
    out[i] = cnt > 0.f ? v / cnt : 0.f;
}

extern "C" void kernel_launch(void* const* d_in, const int* in_sizes, int n_in,
                              void* d_out, int out_size, void* d_ws, size_t ws_size,
                              hipStream_t stream) {
    const float* feat = (const float*)d_in[0];
    const int* seg = (const int*)d_in[1];
    float* out = (float*)d_out;
    float* counts = (float*)d_ws;  // BB*RS floats

    hipMemsetAsync(d_out, 0, (size_t)out_size * sizeof(float), stream);
    hipMemsetAsync(d_ws, 0, (size_t)(BB * RS) * sizeof(float), stream);

    seg_hist<<<dim3((BB * NVOX) / 1024), 256, 0, stream>>>(seg, counts);
    seg_sum<<<dim3(NVOX / CHUNK, TT, BB), 256, 0, stream>>>(feat, seg, out);
    seg_div<<<dim3(out_size / 256), 256, 0, stream>>>(out, counts);
}

// Round 2
// 614.100 us; speedup vs baseline: 1.8336x; 1.8336x over previous
//
#include <hip/hip_runtime.h>

// SubregionFeatureExtractor: per-batch, per-time, per-region channel means.
// features [B,T,C,D,H,W] f32, segmentation [B,1,D,H,W] int32 in 0..32.
// out [B,T,32,C] f32: mean over voxels with seg==r (r=1..32); empty -> 0.
//
// R2 design: lane = channel (64 lanes = 64 channels), voxels walked serially
// in float4 groups. Region ids are wave-uniform per voxel -> LDS accumulate
// is a plain RMW at acc[r*64+lane]: consecutive lane addresses = 2-way bank
// aliasing (free), NO LDS atomics (R1 showed ~236 cyc per ds_add_f32 wave op).

#define BB 2
#define TT 8
#define CC 64
#define NVOX 110592      // 48*48*48
#define NREG 32
#define RS 33            // region slots incl. background 0
#define ACC (RS*CC)      // 2112 floats per wave accumulator copy
#define CHUNKV 1024      // voxels per block
#define VPW (CHUNKV/4)   // 256 voxels per wave (4 waves/block)

// ---------------- kernel 1: per-batch region histogram -------------------
__global__ __launch_bounds__(256) void seg_hist(const int* __restrict__ seg,
                                                float* __restrict__ counts) {
    __shared__ float h[4 * RS];
    const int tid = threadIdx.x;
    const int w = tid >> 6;
    for (int i = tid; i < 4 * RS; i += 256) h[i] = 0.f;
    __syncthreads();

    const int base = blockIdx.x * 1024 + tid * 4;  // flattened over B*NVOX
    const int b = base / NVOX;                      // block fully inside one batch
    const int4 s4 = *(const int4*)(seg + base);
    atomicAdd(&h[w * RS + s4.x], 1.f);
    atomicAdd(&h[w * RS + s4.y], 1.f);
    atomicAdd(&h[w * RS + s4.z], 1.f);
    atomicAdd(&h[w * RS + s4.w], 1.f);
    __syncthreads();

    if (tid < RS) {
        const float v = h[tid] + h[RS + tid] + h[2 * RS + tid] + h[3 * RS + tid];
        atomicAdd(&counts[b * RS + tid], v);
    }
}

// ---------------- kernel 2: streaming region sums ------------------------
// grid: (NVOX/CHUNKV, T, B) = (108, 8, 2) = 1728 blocks, 256 threads.
// Each wave owns 64 channels (lanes) x VPW voxels; private LDS accumulator.
__global__ __launch_bounds__(256) void seg_sum(const float* __restrict__ feat,
                                               const int* __restrict__ seg,
                                               float* __restrict__ out) {
    __shared__ float s[4 * ACC];  // 33792 B -> 4 blocks/CU
    const int tid = threadIdx.x;
    const int w = tid >> 6;
    const int lane = tid & 63;
    const int b = blockIdx.z;
    const int t = blockIdx.y;

    float* __restrict__ acc = s + w * ACC;
    for (int i = lane; i < ACC; i += 64) acc[i] = 0.f;   // wave-private init

    const int v0 = blockIdx.x * CHUNKV + w * VPW;
    // lane's channel stream: feat[b][t][lane][v0 .. v0+VPW)
    const float* __restrict__ fb =
        feat + ((size_t)(b * TT + t) * CC + lane) * NVOX;
    const int* __restrict__ sb = seg + (size_t)b * NVOX;

    #pragma unroll 4
    for (int g = 0; g < VPW; g += 4) {
        const int v = v0 + g;
        const int4 sv = *(const int4*)(sb + v);          // wave-uniform
        const float4 f = *(const float4*)(fb + v);       // lane-strided stream
        acc[sv.x * CC + lane] += f.x;                    // 2-way banks: free
        acc[sv.y * CC + lane] += f.y;
        acc[sv.z * CC + lane] += f.z;
        acc[sv.w * CC + lane] += f.w;
    }
    __syncthreads();

    // merge the 4 wave copies (skip background region 0) -> global atomics
    float* __restrict__ outbt = out + (size_t)(b * TT + t) * NREG * CC;
    for (int i = tid; i < NREG * CC; i += 256) {
        const int off = ((i >> 6) + 1) * CC + (i & 63);  // region 1..32
        const float v = s[off] + s[ACC + off] + s[2 * ACC + off] + s[3 * ACC + off];
        atomicAdd(&outbt[i], v);
    }
}

// ---------------- kernel 3: divide by counts -----------------------------
__global__ __launch_bounds__(256) void seg_div(float* __restrict__ out,
                                               const float* __restrict__ counts) {
    const int i = blockIdx.x * 256 + threadIdx.x;       // out_size = 32768
    const int b = i >> 14;                              // / (TT*NREG*CC)
    const int r = ((i >> 6) & 31) + 1;                  // region 1..32
    const float cnt = counts[b * RS + r];
    const float v = out[i];
    out[i] = cnt > 0.f ? v / cnt : 0.f;
}

extern "C" void kernel_launch(void* const* d_in, const int* in_sizes, int n_in,
                              void* d_out, int out_size, void* d_ws, size_t ws_size,
                              hipStream_t stream) {
    const float* feat = (const float*)d_in[0];
    const int* seg = (const int*)d_in[1];
    float* out = (float*)d_out;
    float* counts = (float*)d_ws;  // BB*RS floats

    hipMemsetAsync(d_out, 0, (size_t)out_size * sizeof(float), stream);
    hipMemsetAsync(d_ws, 0, (size_t)(BB * RS) * sizeof(float), stream);

    seg_hist<<<dim3((BB * NVOX) / 1024), 256, 0, stream>>>(seg, counts);
    seg_sum<<<dim3(NVOX / CHUNKV, TT, BB), 256, 0, stream>>>(feat, seg, out);
    seg_div<<<dim3(out_size / 256), 256, 0, stream>>>(out, counts);
}

// Round 3
// 613.048 us; speedup vs baseline: 1.8368x; 1.0017x over previous
//
#include <hip/hip_runtime.h>

// SubregionFeatureExtractor: per-batch, per-time, per-region channel means.
// features [B,T,C,D,H,W] f32, segmentation [B,1,D,H,W] int32 in 0..32.
// out [B,T,32,C] f32: mean over voxels with seg==r (r=1..32); empty -> 0.
//
// R3: dense global loads (16 fully-used lines/instr) + per-wave LDS transpose
// tile (odd stride 67 -> conflict-free column reads), then wave-uniform-region
// accumulate acc[r*64+lane] += v (2 lanes/bank = free, no atomics).

#define BB 2
#define TT 8
#define CC 64
#define NVOX 110592      // 48*48*48
#define NREG 32
#define RS 33            // region slots incl. background 0
#define TS 67            // tile row stride (floats); odd -> column reads 2-way/free
#define WTILE (16*TS)    // 1072 floats: [16 voxels][64 ch + pad]
#define WACC (RS*CC)     // 2112 floats: [33 regions][64 ch]
#define WLDS (WTILE+WACC) // 3184 floats = 12736 B per wave
#define VPW 256          // voxels per wave
#define CHUNKV 1024      // voxels per block (4 waves)

// ---------------- kernel 1: per-batch region histogram -------------------
__global__ __launch_bounds__(256) void seg_hist(const int* __restrict__ seg,
                                                float* __restrict__ counts) {
    __shared__ float h[4 * RS];
    const int tid = threadIdx.x;
    const int w = tid >> 6;
    for (int i = tid; i < 4 * RS; i += 256) h[i] = 0.f;
    __syncthreads();

    const int base = blockIdx.x * 1024 + tid * 4;  // flattened over B*NVOX
    const int b = base / NVOX;                      // block fully inside one batch
    const int4 s4 = *(const int4*)(seg + base);
    atomicAdd(&h[w * RS + s4.x], 1.f);
    atomicAdd(&h[w * RS + s4.y], 1.f);
    atomicAdd(&h[w * RS + s4.z], 1.f);
    atomicAdd(&h[w * RS + s4.w], 1.f);
    __syncthreads();

    if (tid < RS) {
        const float v = h[tid] + h[RS + tid] + h[2 * RS + tid] + h[3 * RS + tid];
        atomicAdd(&counts[b * RS + tid], v);
    }
}

// ---------------- kernel 2: streaming region sums ------------------------
// grid (NVOX/CHUNKV, T, B) = (108, 8, 2), block 256 (4 waves).
// Wave-private tile+acc; no __syncthreads in the hot loop (wave-synchronous).
__global__ __launch_bounds__(256) void seg_sum(const float* __restrict__ feat,
                                               const int* __restrict__ seg,
                                               float* __restrict__ out) {
    __shared__ float s[4 * WLDS];   // 50944 B -> 3 blocks/CU
    const int tid = threadIdx.x;
    const int w = tid >> 6;
    const int l = tid & 63;
    const int b = blockIdx.z;
    const int t = blockIdx.y;

    float* __restrict__ tile = s + w * WLDS;
    float* __restrict__ acc = tile + WTILE;
    #pragma unroll
    for (int i = l; i < WACC; i += 64) acc[i] = 0.f;   // wave-private init

    const int v0 = blockIdx.x * CHUNKV + w * VPW;
    const int cq = l >> 2;   // 0..15: channel within 16-group
    const int iq = l & 3;    // 0..3: float4 slot (voxels 4*iq..4*iq+3)
    const float* __restrict__ fbt = feat + (size_t)(b * TT + t) * CC * NVOX + v0;
    const float* __restrict__ fp0 = fbt + (size_t)(cq) * NVOX + iq * 4;
    const float* __restrict__ fp1 = fbt + (size_t)(cq + 16) * NVOX + iq * 4;
    const float* __restrict__ fp2 = fbt + (size_t)(cq + 32) * NVOX + iq * 4;
    const float* __restrict__ fp3 = fbt + (size_t)(cq + 48) * NVOX + iq * 4;
    const int* __restrict__ sb = seg + (size_t)b * NVOX + v0;

    const int wb = (iq * 4) * TS + cq;   // staging write base

    #pragma unroll 2
    for (int tj = 0; tj < 16; ++tj) {
        const int vo = tj * 16;
        // dense loads: lanes 0..3 cover one 64B line of one channel stream
        const float4 f0 = *(const float4*)(fp0 + vo);
        const float4 f1 = *(const float4*)(fp1 + vo);
        const float4 f2 = *(const float4*)(fp2 + vo);
        const float4 f3 = *(const float4*)(fp3 + vo);
        const int4 s0 = *(const int4*)(sb + vo);
        const int4 s1 = *(const int4*)(sb + vo + 4);
        const int4 s2 = *(const int4*)(sb + vo + 8);
        const int4 s3 = *(const int4*)(sb + vo + 12);

        __builtin_amdgcn_wave_barrier();  // prior tile reads stay before these writes
        tile[wb] = f0.x;           tile[wb + TS] = f0.y;
        tile[wb + 2 * TS] = f0.z;  tile[wb + 3 * TS] = f0.w;
        tile[wb + 16] = f1.x;          tile[wb + 16 + TS] = f1.y;
        tile[wb + 16 + 2 * TS] = f1.z; tile[wb + 16 + 3 * TS] = f1.w;
        tile[wb + 32] = f2.x;          tile[wb + 32 + TS] = f2.y;
        tile[wb + 32 + 2 * TS] = f2.z; tile[wb + 32 + 3 * TS] = f2.w;
        tile[wb + 48] = f3.x;          tile[wb + 48 + TS] = f3.y;
        tile[wb + 48 + 2 * TS] = f3.z; tile[wb + 48 + 3 * TS] = f3.w;
        __builtin_amdgcn_wave_barrier();  // writes stay before the reads below

        const int rv[16] = {s0.x, s0.y, s0.z, s0.w, s1.x, s1.y, s1.z, s1.w,
                            s2.x, s2.y, s2.z, s2.w, s3.x, s3.y, s3.z, s3.w};
        #pragma unroll
        for (int v = 0; v < 16; ++v) {
            const float val = tile[v * TS + l];        // banks (3v+l)%32: free
            acc[(rv[v] << 6) + l] += val;              // sequential RMW: dup-safe
        }
    }
    __syncthreads();

    // merge the 4 wave copies (skip background region 0) -> global atomics
    float* __restrict__ outbt = out + (size_t)(b * TT + t) * NREG * CC;
    for (int i = tid; i < NREG * CC; i += 256) {
        const int off = WTILE + ((i >> 6) + 1) * CC + (i & 63);  // region 1..32
        const float v = s[off] + s[WLDS + off] + s[2 * WLDS + off] + s[3 * WLDS + off];
        atomicAdd(&outbt[i], v);
    }
}

// ---------------- kernel 3: divide by counts -----------------------------
__global__ __launch_bounds__(256) void seg_div(float* __restrict__ out,
                                               const float* __restrict__ counts) {
    const int i = blockIdx.x * 256 + threadIdx.x;       // out_size = 32768
    const int b = i >> 14;                              // / (TT*NREG*CC)
    const int r = ((i >> 6) & 31) + 1;                  // region 1..32
    const float cnt = counts[b * RS + r];
    const float v = out[i];
    out[i] = cnt > 0.f ? v / cnt : 0.f;
}

extern "C" void kernel_launch(void* const* d_in, const int* in_sizes, int n_in,
                              void* d_out, int out_size, void* d_ws, size_t ws_size,
                              hipStream_t stream) {
    const float* feat = (const float*)d_in[0];
    const int* seg = (const int*)d_in[1];
    float* out = (float*)d_out;
    float* counts = (float*)d_ws;  // BB*RS floats

    hipMemsetAsync(d_out, 0, (size_t)out_size * sizeof(float), stream);
    hipMemsetAsync(d_ws, 0, (size_t)(BB * RS) * sizeof(float), stream);

    seg_hist<<<dim3((BB * NVOX) / 1024), 256, 0, stream>>>(seg, counts);
    seg_sum<<<dim3(NVOX / CHUNKV, TT, BB), 256, 0, stream>>>(feat, seg, out);
    seg_div<<<dim3(out_size / 256), 256, 0, stream>>>(out, counts);
}